// Round 1
// baseline (132.336 us; speedup 1.0000x reference)
//
#include <hip/hip_runtime.h>

typedef unsigned int u32;
typedef unsigned short u16;
typedef __attribute__((ext_vector_type(8))) __bf16 bf16x8;
typedef __attribute__((ext_vector_type(4))) float f32x4;

#define B_SZ 2048
#define IN_SZ 1024
#define K_SZ 128
#define E_SZ 64
#define TWOE 128
static const size_t OUT_EMB = (size_t)B_SZ * K_SZ * E_SZ;  // 16,777,216

__device__ __forceinline__ u16 f2bf(float f) {
    u32 u = __builtin_bit_cast(u32, f);
    u32 r = u + 0x7fffu + ((u >> 16) & 1u);
    return (u16)(r >> 16);
}

__device__ __forceinline__ void async16(const void* g, void* l) {
    __builtin_amdgcn_global_load_lds((const __attribute__((address_space(1))) u32*)g,
                                     (__attribute__((address_space(3))) u32*)l, 16, 0, 0);
}

// ---------------- conversion kernels ----------------
__global__ void __launch_bounds__(256) cvt_x(const float* __restrict__ in, u16* __restrict__ outp, int n4) {
    int i = blockIdx.x * blockDim.x + threadIdx.x;
    if (i < n4) {
        float4 v = ((const float4*)in)[i];
        u32 lo = (u32)f2bf(v.x) | ((u32)f2bf(v.y) << 16);
        u32 hi = (u32)f2bf(v.z) | ((u32)f2bf(v.w) << 16);
        ((uint2*)outp)[i] = make_uint2(lo, hi);
    }
}

// W[k][i][o] f32 -> Wt[k][o][i] bf16.  grid (16 i-blocks, 128 k), 256 thr
__global__ void __launch_bounds__(256) cvt_w(const float* __restrict__ W, u16* __restrict__ wt) {
    __shared__ u16 tr[128][72];  // [o][i], pad 72 keeps rows 16B-aligned
    const int k = blockIdx.y, i0 = blockIdx.x * 64;
    const float* src = W + (size_t)k * IN_SZ * TWOE + (size_t)i0 * TWOE;
#pragma unroll
    for (int r = 0; r < 8; ++r) {
        int idx = r * 256 + threadIdx.x;     // float4 index, 2048 total
        int i = idx >> 5;                    // 32 float4 per 128-wide row
        int o = (idx & 31) * 4;
        float4 v = ((const float4*)src)[idx];
        tr[o + 0][i] = f2bf(v.x);
        tr[o + 1][i] = f2bf(v.y);
        tr[o + 2][i] = f2bf(v.z);
        tr[o + 3][i] = f2bf(v.w);
    }
    __syncthreads();
    const int o = threadIdx.x >> 1, h = threadIdx.x & 1;
    u16* dst = wt + ((size_t)(k * TWOE + o) * IN_SZ) + i0 + h * 32;
#pragma unroll
    for (int s = 0; s < 4; ++s) {
        uint4 v = *(const uint4*)&tr[o][h * 32 + s * 8];
        ((uint4*)dst)[s] = v;
    }
}

// ---------------- fused GEMM + epilogue ----------------
// grid (16 brow-tiles, 128 k), 256 threads (4 waves, 2x2 of 64x64)
__global__ void __launch_bounds__(256) fused_main(
    const u16* __restrict__ xb,   // [B][IN] bf16
    const u16* __restrict__ wt,   // [K][2E][IN] bf16
    const float* __restrict__ bias, const float* __restrict__ wpv,
    const float* __restrict__ bpp, float* __restrict__ out) {
    __shared__ union {
        u16 stage[2][128][64];                       // A then B tile, 16 KB each
        struct { float ex[2][64][65]; float pl[128][2]; } epi;
    } sm;
    u16* smA = &sm.stage[0][0][0];
    u16* smB = &sm.stage[1][0][0];

    const int tid = threadIdx.x;
    const int l = tid & 63, w = tid >> 6;
    const int wm = w >> 1, wn = w & 1;
    const int hi = l >> 4, lo16 = l & 15;
    const int k = blockIdx.y;
    const int brow = blockIdx.x * 128;

    // staging geometry: 16 chunks of (8 rows x 64 cols); wave w owns chunks w*4..w*4+3
    const int lr = l >> 3;        // row within chunk
    const int ls = l & 7;         // 16B slot within row
    f32x4 acc[4][4] = {};

    for (int kt = 0; kt < IN_SZ / 64; ++kt) {
        const int kk = kt * 64;
#pragma unroll
        for (int t = 0; t < 4; ++t) {
            const int row = (w * 4 + t) * 8 + lr;          // 0..127
            const int slotsrc = ls ^ (row & 7);            // inverse swizzle on SOURCE
            async16(xb + (size_t)(brow + row) * IN_SZ + kk + slotsrc * 8,
                    smA + (w * 4 + t) * 512);
            async16(wt + ((size_t)k * TWOE + row) * IN_SZ + kk + slotsrc * 8,
                    smB + (w * 4 + t) * 512);
        }
        __syncthreads();
#pragma unroll
        for (int kk2 = 0; kk2 < 2; ++kk2) {
            bf16x8 af[4], bfr[4];
#pragma unroll
            for (int m = 0; m < 4; ++m) {
                const int row = wm * 64 + m * 16 + lo16;
                const int byteoff = (kk2 * 64 + hi * 16) ^ ((row & 7) << 4);
                af[m] = *(const bf16x8*)((const char*)smA + row * 128 + byteoff);
            }
#pragma unroll
            for (int n = 0; n < 4; ++n) {
                const int row = wn * 64 + n * 16 + lo16;
                const int byteoff = (kk2 * 64 + hi * 16) ^ ((row & 7) << 4);
                bfr[n] = *(const bf16x8*)((const char*)smB + row * 128 + byteoff);
            }
#pragma unroll
            for (int m = 0; m < 4; ++m)
#pragma unroll
                for (int n = 0; n < 4; ++n)
                    acc[m][n] = __builtin_amdgcn_mfma_f32_16x16x32_bf16(af[m], bfr[n], acc[m][n], 0, 0, 0);
        }
        __syncthreads();
    }

    // ---- epilogue ----
    const float bp_val = *bpp;
    float bvals[4], wvals[4];
#pragma unroll
    for (int n = 0; n < 4; ++n) {
        const int o = wn * 64 + n * 16 + lo16;
        bvals[n] = bias[k * TWOE + o];
        wvals[n] = wpv[o];
    }
    // ctx = leaky_relu(acc + bias); per-lane: rows (m,hi,j), cols (n,lo16)
    float ctx[4][4][4];
#pragma unroll
    for (int m = 0; m < 4; ++m)
#pragma unroll
        for (int n = 0; n < 4; ++n)
#pragma unroll
            for (int j = 0; j < 4; ++j) {
                float v = acc[m][n][j] + bvals[n];
                ctx[m][n][j] = v > 0.f ? v : 0.01f * v;
            }
    // per-row partial dot over this wave's 64 cols
    float ps[4][4];
#pragma unroll
    for (int m = 0; m < 4; ++m)
#pragma unroll
        for (int j = 0; j < 4; ++j) {
            float s = 0.f;
#pragma unroll
            for (int n = 0; n < 4; ++n) s += ctx[m][n][j] * wvals[n];
            s += __shfl_xor(s, 1);
            s += __shfl_xor(s, 2);
            s += __shfl_xor(s, 4);
            s += __shfl_xor(s, 8);
            ps[m][j] = s;
        }
    // exchange partials across wn (stage buffer is dead: loop ended with barrier)
    if (lo16 == 0) {
#pragma unroll
        for (int m = 0; m < 4; ++m)
#pragma unroll
            for (int j = 0; j < 4; ++j)
                sm.epi.pl[wm * 64 + m * 16 + hi * 4 + j][wn] = ps[m][j];
    }
    __syncthreads();
    float pr[4][4];
#pragma unroll
    for (int m = 0; m < 4; ++m)
#pragma unroll
        for (int j = 0; j < 4; ++j) {
            const int r = wm * 64 + m * 16 + hi * 4 + j;
            float z = sm.epi.pl[r][0] + sm.epi.pl[r][1] + bp_val;
            pr[m][j] = 1.f / (1.f + expf(-z));
        }
    // wn==1 owns ctx_neg (o=64..127): ship (1-p)*ctx_neg through LDS
    if (wn == 1) {
#pragma unroll
        for (int m = 0; m < 4; ++m)
#pragma unroll
            for (int n = 0; n < 4; ++n)
#pragma unroll
                for (int j = 0; j < 4; ++j)
                    sm.epi.ex[wm][m * 16 + hi * 4 + j][n * 16 + lo16] =
                        (1.f - pr[m][j]) * ctx[m][n][j];
    }
    if (wn == 0 && lo16 == 0) {
#pragma unroll
        for (int m = 0; m < 4; ++m)
#pragma unroll
            for (int j = 0; j < 4; ++j) {
                const int b = brow + wm * 64 + m * 16 + hi * 4 + j;
                out[OUT_EMB + (size_t)b * K_SZ + k] = pr[m][j];
            }
    }
    __syncthreads();
    if (wn == 0) {
#pragma unroll
        for (int m = 0; m < 4; ++m)
#pragma unroll
            for (int n = 0; n < 4; ++n)
#pragma unroll
                for (int j = 0; j < 4; ++j) {
                    const int rl = m * 16 + hi * 4 + j;
                    const int b = brow + wm * 64 + rl;
                    const int e = n * 16 + lo16;
                    float v = pr[m][j] * ctx[m][n][j] + sm.epi.ex[wm][rl][e];
                    out[((size_t)b * K_SZ + k) * E_SZ + e] = v;
                }
    }
}

// ---------------- no-ws fallback (correctness insurance) ----------------
__global__ void __launch_bounds__(128) fallback_kernel(
    const float* __restrict__ x, const float* __restrict__ W,
    const float* __restrict__ bias, const float* __restrict__ wpv,
    const float* __restrict__ bpp, float* __restrict__ out) {
    const int k = blockIdx.y;
    const int b0 = blockIdx.x * 8;
    const int o = threadIdx.x;
    __shared__ float xs[8][1024];
    __shared__ float red[2];
    __shared__ float exch[64];
    for (int idx = threadIdx.x; idx < 8 * 1024; idx += 128)
        xs[idx >> 10][idx & 1023] = x[(size_t)(b0 + (idx >> 10)) * IN_SZ + (idx & 1023)];
    __syncthreads();
    float a[8] = {};
    for (int i = 0; i < 1024; ++i) {
        float wv = W[((size_t)k * IN_SZ + i) * TWOE + o];
#pragma unroll
        for (int bb = 0; bb < 8; ++bb) a[bb] += xs[bb][i] * wv;
    }
    const float bo = bias[k * TWOE + o], wo = wpv[o], bpv = *bpp;
    for (int bb = 0; bb < 8; ++bb) {
        float c = a[bb] + bo;
        c = c > 0.f ? c : 0.01f * c;
        float s = c * wo;
        for (int off = 1; off < 64; off <<= 1) s += __shfl_xor(s, off);
        if ((threadIdx.x & 63) == 0) red[threadIdx.x >> 6] = s;
        __syncthreads();
        float p = 1.f / (1.f + expf(-(red[0] + red[1] + bpv)));
        if (o >= 64) exch[o - 64] = (1.f - p) * c;
        __syncthreads();
        if (o < 64) out[((size_t)(b0 + bb) * K_SZ + k) * E_SZ + o] = p * c + exch[o];
        if (o == 0) out[OUT_EMB + (size_t)(b0 + bb) * K_SZ + k] = p;
        __syncthreads();
    }
}

extern "C" void kernel_launch(void* const* d_in, const int* in_sizes, int n_in,
                              void* d_out, int out_size, void* d_ws, size_t ws_size,
                              hipStream_t stream) {
    const float* x = (const float*)d_in[0];
    const float* W = (const float*)d_in[1];
    const float* bias = (const float*)d_in[2];
    const float* wp = (const float*)d_in[3];
    const float* bp = (const float*)d_in[4];
    float* out = (float*)d_out;

    const size_t X_ELEMS = (size_t)B_SZ * IN_SZ;              // 2M
    const size_t WT_ELEMS = (size_t)K_SZ * TWOE * IN_SZ;      // 16.78M
    const size_t NEED = (X_ELEMS + WT_ELEMS) * sizeof(u16);   // ~36 MB

    if (ws_size >= NEED) {
        u16* xb = (u16*)d_ws;
        u16* wt = xb + X_ELEMS;
        int n4 = (int)(X_ELEMS / 4);
        cvt_x<<<dim3((n4 + 255) / 256), 256, 0, stream>>>(x, xb, n4);
        cvt_w<<<dim3(16, 128), 256, 0, stream>>>(W, wt);
        fused_main<<<dim3(16, 128), 256, 0, stream>>>(xb, wt, bias, wp, bp, out);
    } else {
        fallback_kernel<<<dim3(B_SZ / 8, K_SZ), 128, 0, stream>>>(x, W, bias, wp, bp, out);
    }
}

// Round 2
// 119.367 us; speedup vs baseline: 1.1086x; 1.1086x over previous
//
#include <hip/hip_runtime.h>

typedef unsigned int u32;
typedef unsigned short u16;
typedef __attribute__((ext_vector_type(8))) __bf16 bf16x8;
typedef __attribute__((ext_vector_type(4))) float f32x4;

#define B_SZ 2048
#define IN_SZ 1024
#define K_SZ 128
#define E_SZ 64
#define TWOE 128
#define BK 32
static const size_t OUT_EMB = (size_t)B_SZ * K_SZ * E_SZ;  // 16,777,216

__device__ __forceinline__ u16 f2bf(float f) {
    u32 u = __builtin_bit_cast(u32, f);
    u32 r = u + 0x7fffu + ((u >> 16) & 1u);
    return (u16)(r >> 16);
}

__device__ __forceinline__ void async16(const void* g, void* l) {
    __builtin_amdgcn_global_load_lds((const __attribute__((address_space(1))) u32*)g,
                                     (__attribute__((address_space(3))) u32*)l, 16, 0, 0);
}

// ---------------- conversion kernels ----------------
__global__ void __launch_bounds__(256) cvt_x(const float* __restrict__ in, u16* __restrict__ outp, int n4) {
    int i = blockIdx.x * blockDim.x + threadIdx.x;
    if (i < n4) {
        float4 v = ((const float4*)in)[i];
        u32 lo = (u32)f2bf(v.x) | ((u32)f2bf(v.y) << 16);
        u32 hi = (u32)f2bf(v.z) | ((u32)f2bf(v.w) << 16);
        ((uint2*)outp)[i] = make_uint2(lo, hi);
    }
}

// W[k][i][o] f32 -> Wt[k][o][i] bf16.  grid (16 i-blocks, 128 k), 256 thr
__global__ void __launch_bounds__(256) cvt_w(const float* __restrict__ W, u16* __restrict__ wt) {
    __shared__ u16 tr[128][72];
    const int k = blockIdx.y, i0 = blockIdx.x * 64;
    const float* src = W + (size_t)k * IN_SZ * TWOE + (size_t)i0 * TWOE;
#pragma unroll
    for (int r = 0; r < 8; ++r) {
        int idx = r * 256 + threadIdx.x;
        int i = idx >> 5;
        int o = (idx & 31) * 4;
        float4 v = ((const float4*)src)[idx];
        tr[o + 0][i] = f2bf(v.x);
        tr[o + 1][i] = f2bf(v.y);
        tr[o + 2][i] = f2bf(v.z);
        tr[o + 3][i] = f2bf(v.w);
    }
    __syncthreads();
    const int o = threadIdx.x >> 1, h = threadIdx.x & 1;
    u16* dst = wt + ((size_t)(k * TWOE + o) * IN_SZ) + i0 + h * 32;
#pragma unroll
    for (int s = 0; s < 4; ++s) {
        uint4 v = *(const uint4*)&tr[o][h * 32 + s * 8];
        ((uint4*)dst)[s] = v;
    }
}

// ---------------- fused GEMM + epilogue ----------------
// BM=512, BN=128(=TWOE), BK=32. 512 threads = 8 waves (4M x 2N), per-wave 128x64.
// 3-buffer LDS ring, counted vmcnt(5) (loads for tile t+2 in flight across barrier).
// grid: 512 blocks (4 brow x 128 k), XCD-chunked so each XCD owns 16 consecutive k.
__global__ void __launch_bounds__(512, 2) fused_main(
    const u16* __restrict__ xb,   // [B][IN] bf16
    const u16* __restrict__ wt,   // [K][2E][IN] bf16
    const float* __restrict__ bias, const float* __restrict__ wpv,
    const float* __restrict__ bpp, float* __restrict__ out) {
    __shared__ union {
        u16 stage[3][20480];   // per buf: A[512][32] @ u16 0, B[128][32] @ u16 16384
        struct { float pl[512][2]; float ex[256][65]; } epi;
    } sm;

    const int tid = threadIdx.x;
    const int l = tid & 63, w = tid >> 6;   // lane, wave 0..7
    const int wm = w >> 1, wn = w & 1;      // 4M x 2N
    const int hi = l >> 4, lo16 = l & 15;
    const int q = l >> 2, sl = l & 3;       // staging: row-in-16, 16B slot

    // XCD-aware (k,brow) mapping: block id round-robins XCDs; give each XCD 16 k's
    const int id = blockIdx.x;
    const int xcd = id & 7, j = id >> 3;
    const int k = (xcd << 4) | (j >> 2);
    const int brow = (j & 3) << 9;          // *512

    // staging bases: source pre-swizzled (slot ^ (row&3)), LDS dest linear
    const u16* abase = xb + (size_t)(brow + w * 16 + q) * IN_SZ + (sl ^ (q & 3)) * 8;
    const u16* bbase = wt + ((size_t)k * TWOE + w * 16 + q) * IN_SZ + (sl ^ (q & 3)) * 8;
    const int aldst = w * 512;              // u16 units; + i*4096
    const int bldst = 16384 + w * 512;

    // ds_read fragment offsets (bytes), swizzled to match staging
    const int xsl = (hi ^ (lo16 & 3)) << 4;
    const int aoff = (wm * 128 + lo16) * 64 + xsl;         // + m*1024
    const int boff = 32768 + (wn * 64 + lo16) * 64 + xsl;  // + n*1024

    f32x4 acc[8][4] = {};

    auto STAGE = [&](int bi, int tt) {
        const int koff = tt * BK;
        u16* sbuf = &sm.stage[bi][0];
#pragma unroll
        for (int i = 0; i < 4; ++i)
            async16(abase + (size_t)i * 128 * IN_SZ + koff, sbuf + i * 4096 + aldst);
        async16(bbase + koff, sbuf + bldst);
    };

    STAGE(0, 0);
    STAGE(1, 1);
    asm volatile("s_waitcnt vmcnt(5)" ::: "memory");
    __builtin_amdgcn_s_barrier();

    for (int t = 0; t < 32; ++t) {
        const int b0 = t % 3;
        if (t < 30) STAGE((b0 + 2) % 3, t + 2);   // tile t+2 into ring slot
        const char* base = (const char*)&sm.stage[b0][0];
        bf16x8 af[8], bfr[4];
#pragma unroll
        for (int m = 0; m < 8; ++m)
            af[m] = *(const bf16x8*)(base + aoff + m * 1024);
#pragma unroll
        for (int n = 0; n < 4; ++n)
            bfr[n] = *(const bf16x8*)(base + boff + n * 1024);
#pragma unroll
        for (int m = 0; m < 8; ++m)
#pragma unroll
            for (int n = 0; n < 4; ++n)
                acc[m][n] = __builtin_amdgcn_mfma_f32_16x16x32_bf16(af[m], bfr[n], acc[m][n], 0, 0, 0);
        // t+1's 5 loads must be done; t+2's 5 stay in flight (counted vmcnt, T4)
        if (t < 30) asm volatile("s_waitcnt vmcnt(5) lgkmcnt(0)" ::: "memory");
        else        asm volatile("s_waitcnt vmcnt(0) lgkmcnt(0)" ::: "memory");
        __builtin_amdgcn_s_barrier();
    }

    // ---- epilogue ----
    const float bp_val = *bpp;
    float bvals[4], wvals[4];
#pragma unroll
    for (int n = 0; n < 4; ++n) {
        const int o = wn * 64 + n * 16 + lo16;
        bvals[n] = bias[k * TWOE + o];
        wvals[n] = wpv[o];
    }
    float p[8][4];   // first: dot partial; after sigmoid: c_pred
#pragma unroll
    for (int m = 0; m < 8; ++m)
#pragma unroll
        for (int j = 0; j < 4; ++j) {
            float s = 0.f;
#pragma unroll
            for (int n = 0; n < 4; ++n) {
                float v = acc[m][n][j] + bvals[n];
                v = v > 0.f ? v : 0.01f * v;
                acc[m][n][j] = v;           // ctx stored back into acc
                s += v * wvals[n];
            }
            s += __shfl_xor(s, 1);
            s += __shfl_xor(s, 2);
            s += __shfl_xor(s, 4);
            s += __shfl_xor(s, 8);
            p[m][j] = s;
        }
    if (lo16 == 0) {
#pragma unroll
        for (int m = 0; m < 8; ++m)
#pragma unroll
            for (int j = 0; j < 4; ++j)
                sm.epi.pl[wm * 128 + m * 16 + hi * 4 + j][wn] = p[m][j];
    }
    __builtin_amdgcn_s_barrier();
#pragma unroll
    for (int m = 0; m < 8; ++m)
#pragma unroll
        for (int j = 0; j < 4; ++j) {
            const int rg = wm * 128 + m * 16 + hi * 4 + j;
            const float z = sm.epi.pl[rg][0] + sm.epi.pl[rg][1] + bp_val;
            p[m][j] = 1.f / (1.f + __expf(-z));
        }
    if (wn == 0 && lo16 == 0) {
#pragma unroll
        for (int m = 0; m < 8; ++m)
#pragma unroll
            for (int j = 0; j < 4; ++j) {
                const int b = brow + wm * 128 + m * 16 + hi * 4 + j;
                out[OUT_EMB + (size_t)b * K_SZ + k] = p[m][j];
            }
    }
    // c_emb in two 64-row halves per wave (ex fits 256x65 f32)
#pragma unroll
    for (int h = 0; h < 2; ++h) {
        if (wn == 1) {
#pragma unroll
            for (int mm = 0; mm < 4; ++mm) {
                const int m = h * 4 + mm;
#pragma unroll
                for (int n = 0; n < 4; ++n)
#pragma unroll
                    for (int j = 0; j < 4; ++j)
                        sm.epi.ex[wm * 64 + mm * 16 + hi * 4 + j][n * 16 + lo16] =
                            (1.f - p[m][j]) * acc[m][n][j];
            }
        }
        __builtin_amdgcn_s_barrier();
        if (wn == 0) {
#pragma unroll
            for (int mm = 0; mm < 4; ++mm) {
                const int m = h * 4 + mm;
#pragma unroll
                for (int n = 0; n < 4; ++n)
#pragma unroll
                    for (int j = 0; j < 4; ++j) {
                        const int rl = wm * 64 + mm * 16 + hi * 4 + j;
                        const int b = brow + wm * 128 + m * 16 + hi * 4 + j;
                        const int e = n * 16 + lo16;
                        out[((size_t)b * K_SZ + k) * E_SZ + e] =
                            p[m][j] * acc[m][n][j] + sm.epi.ex[rl][e];
                    }
            }
        }
        __builtin_amdgcn_s_barrier();
    }
}

// ---------------- no-ws fallback (correctness insurance) ----------------
__global__ void __launch_bounds__(128) fallback_kernel(
    const float* __restrict__ x, const float* __restrict__ W,
    const float* __restrict__ bias, const float* __restrict__ wpv,
    const float* __restrict__ bpp, float* __restrict__ out) {
    const int k = blockIdx.y;
    const int b0 = blockIdx.x * 8;
    const int o = threadIdx.x;
    __shared__ float xs[8][1024];
    __shared__ float red[2];
    __shared__ float exch[64];
    for (int idx = threadIdx.x; idx < 8 * 1024; idx += 128)
        xs[idx >> 10][idx & 1023] = x[(size_t)(b0 + (idx >> 10)) * IN_SZ + (idx & 1023)];
    __syncthreads();
    float a[8] = {};
    for (int i = 0; i < 1024; ++i) {
        float wv = W[((size_t)k * IN_SZ + i) * TWOE + o];
#pragma unroll
        for (int bb = 0; bb < 8; ++bb) a[bb] += xs[bb][i] * wv;
    }
    const float bo = bias[k * TWOE + o], wo = wpv[o], bpv = *bpp;
    for (int bb = 0; bb < 8; ++bb) {
        float c = a[bb] + bo;
        c = c > 0.f ? c : 0.01f * c;
        float s = c * wo;
        for (int off = 1; off < 64; off <<= 1) s += __shfl_xor(s, off);
        if ((threadIdx.x & 63) == 0) red[threadIdx.x >> 6] = s;
        __syncthreads();
        float p = 1.f / (1.f + expf(-(red[0] + red[1] + bpv)));
        if (o >= 64) exch[o - 64] = (1.f - p) * c;
        __syncthreads();
        if (o < 64) out[((size_t)(b0 + bb) * K_SZ + k) * E_SZ + o] = p * c + exch[o];
        if (o == 0) out[OUT_EMB + (size_t)(b0 + bb) * K_SZ + k] = p;
        __syncthreads();
    }
}

extern "C" void kernel_launch(void* const* d_in, const int* in_sizes, int n_in,
                              void* d_out, int out_size, void* d_ws, size_t ws_size,
                              hipStream_t stream) {
    const float* x = (const float*)d_in[0];
    const float* W = (const float*)d_in[1];
    const float* bias = (const float*)d_in[2];
    const float* wp = (const float*)d_in[3];
    const float* bp = (const float*)d_in[4];
    float* out = (float*)d_out;

    const size_t X_ELEMS = (size_t)B_SZ * IN_SZ;
    const size_t WT_ELEMS = (size_t)K_SZ * TWOE * IN_SZ;
    const size_t NEED = (X_ELEMS + WT_ELEMS) * sizeof(u16);

    if (ws_size >= NEED) {
        u16* xb = (u16*)d_ws;
        u16* wt = xb + X_ELEMS;
        int n4 = (int)(X_ELEMS / 4);
        cvt_x<<<dim3((n4 + 255) / 256), 256, 0, stream>>>(x, xb, n4);
        cvt_w<<<dim3(16, 128), 256, 0, stream>>>(W, wt);
        fused_main<<<dim3(512), 512, 0, stream>>>(xb, wt, bias, wp, bp, out);
    } else {
        fallback_kernel<<<dim3(B_SZ / 8, K_SZ), 128, 0, stream>>>(x, W, bias, wp, bp, out);
    }
}